// Round 3
// baseline (12490.056 us; speedup 1.0000x reference)
//
#include <hip/hip_runtime.h>
#include <math.h>

static constexpr int HWo   = 3136;   // 56*56
static constexpr int NB    = 8;
static constexpr int KDIM  = 1794;   // 1792 + 2 coord channels
static constexpr int ODIM  = 1792;
static constexpr int NCENT = 3136;

// ---------------- cent[j] = sum_o C[o][j]^2 ----------------
__global__ __launch_bounds__(256) void cent_kernel(const float* __restrict__ Cm, float* __restrict__ cent) {
  int j = blockIdx.x * 256 + threadIdx.x;
  if (j >= NCENT) return;
  float s = 0.f;
  for (int o = 0; o < ODIM; ++o) { float v = Cm[(size_t)o * NCENT + j]; s += v * v; }
  cent[j] = s;
}

// ---------------- descriptor build (pool + bilinear fused, per batch) ----------------
__device__ __forceinline__ float pool9(const float* __restrict__ p, int S, int y, int x) {
  float s = 0.f;
  for (int dy = -1; dy <= 1; ++dy) {
    int yy = y + dy; if (yy < 0 || yy >= S) continue;
    for (int dx = -1; dx <= 1; ++dx) {
      int xx = x + dx; if (xx < 0 || xx >= S) continue;
      s += p[yy * S + xx];
    }
  }
  return s * (1.f / 9.f);
}

__device__ __forceinline__ float poolbil(const float* __restrict__ p, int S, float scale, float shift,
                                         int y, int x) {
  float sx = x * scale + shift, sy = y * scale + shift;
  float fx0 = floorf(sx), fy0 = floorf(sy);
  float fx = sx - fx0, fy = sy - fy0;
  int x0 = (int)fx0, y0 = (int)fy0, x1 = x0 + 1, y1 = y0 + 1;
  x0 = x0 < 0 ? 0 : (x0 > S - 1 ? S - 1 : x0);
  x1 = x1 < 0 ? 0 : (x1 > S - 1 ? S - 1 : x1);
  y0 = y0 < 0 ? 0 : (y0 > S - 1 ? S - 1 : y0);
  y1 = y1 < 0 ? 0 : (y1 > S - 1 ? S - 1 : y1);
  float v00 = pool9(p, S, y0, x0), v01 = pool9(p, S, y0, x1);
  float v10 = pool9(p, S, y1, x0), v11 = pool9(p, S, y1, x1);
  return (1.f - fy) * ((1.f - fx) * v00 + fx * v01) + fy * ((1.f - fx) * v10 + fx * v11);
}

__global__ __launch_bounds__(256) void build_xc_kernel(const float* __restrict__ p1, const float* __restrict__ p2,
                                                       const float* __restrict__ p3, float* __restrict__ xcb, int b) {
  int idx = blockIdx.x * 256 + threadIdx.x;
  if (idx >= KDIM * HWo) return;
  int ch = idx / HWo, hw = idx % HWo;
  int x = hw % 56, y = hw / 56;
  float v;
  if (ch < 256)        v = pool9(p1 + (size_t)(b * 256 + ch) * HWo, 56, y, x);
  else if (ch < 768)   v = poolbil(p2 + (size_t)(b * 512 + (ch - 256)) * 784, 28, 0.5f, -0.25f, y, x);
  else if (ch < 1792)  v = poolbil(p3 + (size_t)(b * 1024 + (ch - 768)) * 196, 14, 0.25f, -0.375f, y, x);
  else if (ch == 1792) v = -1.f + 2.f * x / 55.f;
  else                 v = -1.f + 2.f * y / 55.f;
  xcb[idx] = v;
}

// ---------------- GEMM1 per batch: phi_b[o][n] = sum_c W[o][c]*xcb[c][n] + bias[o] ----------------
__global__ __launch_bounds__(256) void gemm1_kernel(const float* __restrict__ Wm, const float* __restrict__ bias,
                                                    const float* __restrict__ xcb, float* __restrict__ phi_b) {
  __shared__ float As[16][68];
  __shared__ float Bs[16][68];
  int t = threadIdx.x;
  int row0 = blockIdx.y * 64, col0 = blockIdx.x * 64;
  int tm = t >> 4, tn = t & 15;
  float acc[4][4] = {};
  for (int k0 = 0; k0 < KDIM; k0 += 16) {
    #pragma unroll
    for (int l = 0; l < 4; ++l) {
      int li = l * 256 + t;
      int k = li & 15, m = li >> 4;     // consecutive t -> consecutive k along W rows
      int gk = k0 + k;
      As[k][m] = (gk < KDIM) ? Wm[(size_t)(row0 + m) * KDIM + gk] : 0.f;
    }
    #pragma unroll
    for (int l = 0; l < 4; ++l) {
      int li = l * 256 + t;
      int n = li & 63, k = li >> 6;     // consecutive t -> consecutive n (coalesced)
      int gk = k0 + k;
      Bs[k][n] = (gk < KDIM) ? xcb[(size_t)gk * HWo + col0 + n] : 0.f;
    }
    __syncthreads();
    #pragma unroll
    for (int kk = 0; kk < 16; ++kk) {
      float a[4], bb[4];
      #pragma unroll
      for (int i = 0; i < 4; ++i) a[i] = As[kk][tm * 4 + i];
      #pragma unroll
      for (int j = 0; j < 4; ++j) bb[j] = Bs[kk][tn * 4 + j];
      #pragma unroll
      for (int i = 0; i < 4; ++i)
        #pragma unroll
        for (int j = 0; j < 4; ++j)
          acc[i][j] += a[i] * bb[j];
    }
    __syncthreads();
  }
  #pragma unroll
  for (int i = 0; i < 4; ++i) {
    int row = row0 + tm * 4 + i;
    float bv = bias[row];
    #pragma unroll
    for (int j = 0; j < 4; ++j)
      phi_b[(size_t)row * HWo + col0 + tn * 4 + j] = acc[i][j] + bv;
  }
}

// ---------------- feat[r] = sum_o phi_b[o][r]^2 ----------------
__global__ __launch_bounds__(256) void feat_kernel(const float* __restrict__ phi_b, float* __restrict__ feat) {
  int r = blockIdx.x * 256 + threadIdx.x;
  if (r >= HWo) return;
  float s = 0.f;
  for (int o = 0; o < ODIM; ++o) { float v = phi_b[(size_t)o * HWo + r]; s += v * v; }
  feat[r] = s;
}

// ---------------- GEMM2 partial: per (row-tile, col-chunk) top-3 of key = cent - 2*dot ----------------
__device__ __forceinline__ void ins3(float v, float& a, float& b, float& c) {
  if (v < c) {
    if (v < b) { c = b; if (v < a) { b = a; a = v; } else { b = v; } }
    else { c = v; }
  }
}

// grid: (7 col-chunks, 98 row-tiles). Each block: 32 rows x 448 cols (7 tiles of 64), K=1792.
__global__ __launch_bounds__(256) void gemm2_part_kernel(const float* __restrict__ phi_b, const float* __restrict__ Cm,
                                                         const float* __restrict__ cent, float* __restrict__ part) {
  __shared__ float As[16][34];
  __shared__ float Bs[16][68];
  int t = threadIdx.x;
  int chunk = blockIdx.x;          // [0,7)
  int r0 = blockIdx.y * 32;        // row base
  int tm = t >> 4, tn = t & 15;    // tm: 16 row-groups (2 rows); tn: 16 col-groups (4 cols)

  float t0[2] = {3.4e38f, 3.4e38f}, t1[2] = {3.4e38f, 3.4e38f}, t2[2] = {3.4e38f, 3.4e38f};

  for (int ct = 0; ct < 7; ++ct) {
    int c0 = chunk * 448 + ct * 64;
    float acc[2][4] = {};
    for (int k0 = 0; k0 < ODIM; k0 += 16) {
      #pragma unroll
      for (int l = 0; l < 2; ++l) {              // 16x32 phi tile
        int li = l * 256 + t;
        int m = li & 31, k = li >> 5;
        As[k][m] = phi_b[(size_t)(k0 + k) * HWo + r0 + m];
      }
      #pragma unroll
      for (int l = 0; l < 4; ++l) {              // 16x64 C tile
        int li = l * 256 + t;
        int n = li & 63, k = li >> 6;
        Bs[k][n] = Cm[(size_t)(k0 + k) * NCENT + c0 + n];
      }
      __syncthreads();
      #pragma unroll
      for (int kk = 0; kk < 16; ++kk) {
        float a0 = As[kk][tm * 2], a1 = As[kk][tm * 2 + 1];
        float bb[4];
        #pragma unroll
        for (int j = 0; j < 4; ++j) bb[j] = Bs[kk][tn * 4 + j];
        #pragma unroll
        for (int j = 0; j < 4; ++j) { acc[0][j] += a0 * bb[j]; acc[1][j] += a1 * bb[j]; }
      }
      __syncthreads();
    }
    #pragma unroll
    for (int i = 0; i < 2; ++i)
      #pragma unroll
      for (int j = 0; j < 4; ++j) {
        float key = cent[c0 + tn * 4 + j] - 2.f * acc[i][j];  // rank-equal to dist^2 (feat added later)
        ins3(key, t0[i], t1[i], t2[i]);
      }
  }

  // merge across the 16 tn-threads of each row (consecutive lanes within one wave)
  #pragma unroll
  for (int m = 1; m < 16; m <<= 1) {
    #pragma unroll
    for (int i = 0; i < 2; ++i) {
      float u0 = __shfl_xor(t0[i], m, 64);
      float u1 = __shfl_xor(t1[i], m, 64);
      float u2 = __shfl_xor(t2[i], m, 64);
      ins3(u0, t0[i], t1[i], t2[i]);
      ins3(u1, t0[i], t1[i], t2[i]);
      ins3(u2, t0[i], t1[i], t2[i]);
    }
  }

  if (tn == 0) {
    #pragma unroll
    for (int i = 0; i < 2; ++i) {
      int row = r0 + tm * 2 + i;
      float* p = part + (size_t)row * 21 + chunk * 3;
      p[0] = t0[i]; p[1] = t1[i]; p[2] = t2[i];
    }
  }
}

// ---------------- final merge + softmin score ----------------
__global__ __launch_bounds__(256) void score_kernel(const float* __restrict__ part, const float* __restrict__ feat,
                                                    float* __restrict__ out, int b) {
  int r = blockIdx.x * 256 + threadIdx.x;
  if (r >= HWo) return;
  const float* p = part + (size_t)r * 21;
  float t0 = 3.4e38f, t1 = 3.4e38f, t2 = 3.4e38f;
  #pragma unroll
  for (int q = 0; q < 21; ++q) ins3(p[q], t0, t1, t2);
  float ft = feat[r];
  float v0 = sqrtf(fmaxf(ft + t0, 0.f));
  float v1 = sqrtf(fmaxf(ft + t1, 0.f));
  float v2 = sqrtf(fmaxf(ft + t2, 0.f));
  float w0 = 1.f / (1.f + expf(v0 - v1) + expf(v0 - v2));   // softmin weight of smallest
  out[b * HWo + r] = v0 * w0;
}

// ---------------- launch ----------------
extern "C" void kernel_launch(void* const* d_in, const int* in_sizes, int n_in,
                              void* d_out, int out_size, void* d_ws, size_t ws_size,
                              hipStream_t stream) {
  const float* p1   = (const float*)d_in[0];
  const float* p2   = (const float*)d_in[1];
  const float* p3   = (const float*)d_in[2];
  const float* Wm   = (const float*)d_in[3];
  const float* bias = (const float*)d_in[4];
  const float* Cm   = (const float*)d_in[5];
  float* out = (float*)d_out;

  // workspace layout (~45.3 MB total)
  char* ws = (char*)d_ws;
  float* cent  = (float*)ws;                              // 3136*4      -> pad 16384
  float* feat  = (float*)(ws + 16384);                    // 3136*4      -> pad 16384
  float* part  = (float*)(ws + 32768);                    // 3136*21*4 = 263424 -> pad 270336
  float* xcb   = (float*)(ws + 32768 + 270336);           // 1794*3136*4 = 22505472
  float* phi_b = (float*)(ws + 32768 + 270336 + 22505472);// 1792*3136*4 = 22480896

  cent_kernel<<<(NCENT + 255) / 256, 256, 0, stream>>>(Cm, cent);

  const int bx_blocks = (KDIM * HWo + 255) / 256;
  for (int b = 0; b < NB; ++b) {
    build_xc_kernel<<<bx_blocks, 256, 0, stream>>>(p1, p2, p3, xcb, b);
    gemm1_kernel<<<dim3(HWo / 64, ODIM / 64), 256, 0, stream>>>(Wm, bias, xcb, phi_b);
    feat_kernel<<<(HWo + 255) / 256, 256, 0, stream>>>(phi_b, feat);
    gemm2_part_kernel<<<dim3(7, HWo / 32), 256, 0, stream>>>(phi_b, Cm, cent, part);
    score_kernel<<<(HWo + 255) / 256, 256, 0, stream>>>(part, feat, out, b);
  }
}

// Round 4
// 1833.833 us; speedup vs baseline: 6.8109x; 6.8109x over previous
//
#include <hip/hip_runtime.h>
#include <math.h>
#include <stdint.h>

typedef float f32x4 __attribute__((ext_vector_type(4)));
typedef short short8 __attribute__((ext_vector_type(8)));

static constexpr int HWo   = 3136;   // 56*56
static constexpr int NB    = 8;
static constexpr int NP    = 3200;   // padded pixel / centroid count (25*128)
static constexpr int KDIM  = 1794;   // 1792 + 2 coord channels
static constexpr int KP1   = 1856;   // gemm1 K padded to 29*64
static constexpr int ODIM  = 1792;   // gemm2 K = 28*64
static constexpr int NCENT = 3136;

__device__ __forceinline__ uint16_t f2bf(float f) {
  union { float f; uint32_t u; } v; v.f = f;
  uint32_t u = v.u;
  return (uint16_t)((u + 0x7FFFu + ((u >> 16) & 1u)) >> 16);   // RNE
}
__device__ __forceinline__ float bf2f(uint16_t h) {
  union { uint32_t u; float f; } v; v.u = ((uint32_t)h) << 16;
  return v.f;
}

// ---------------- one-time converts ----------------
// W fp32 [1792][1794] -> Wh bf16 [1792][1856], zero-pad k>=1794
__global__ __launch_bounds__(256) void convW_kernel(const float* __restrict__ W, uint16_t* __restrict__ Wh) {
  int idx = blockIdx.x * 256 + threadIdx.x;          // 1792*1856 exact
  int o = idx / KP1, k = idx % KP1;
  float v = (k < KDIM) ? W[(size_t)o * KDIM + k] : 0.f;
  Wh[idx] = f2bf(v);
}

// C fp32 [1792][3136] -> Ct bf16 [3136][1792] (transpose; rows 3136..3199 stay poison=finite)
__global__ __launch_bounds__(256) void convC_kernel(const float* __restrict__ C, uint16_t* __restrict__ Ct) {
  int idx = blockIdx.x * 256 + threadIdx.x;          // 3136*1792 exact
  int j = idx / ODIM, o = idx % ODIM;
  Ct[(size_t)j * ODIM + o] = f2bf(C[(size_t)o * NCENT + j]);
}

// ---------------- row squared-norms of a bf16 [3136][1792] matrix ----------------
__global__ __launch_bounds__(256) void rownorm_kernel(const uint16_t* __restrict__ src, float* __restrict__ dst) {
  int t = threadIdx.x, lane = t & 63, wave = t >> 6;
  int row = blockIdx.x * 4 + wave;                   // 784 blocks * 4 = 3136
  const uint32_t* p = (const uint32_t*)(src + (size_t)row * ODIM);
  float s = 0.f;
  #pragma unroll
  for (int it = 0; it < 14; ++it) {                  // 896 uint pairs / 64 lanes
    uint32_t u = p[it * 64 + lane];
    float a = bf2f((uint16_t)(u & 0xFFFF)), b = bf2f((uint16_t)(u >> 16));
    s += a * a + b * b;
  }
  #pragma unroll
  for (int m = 1; m < 64; m <<= 1) s += __shfl_xor(s, m, 64);
  if (lane == 0) dst[row] = s;
}

// ---------------- pooling (all 3 levels, native res, fp32) ----------------
static constexpr int P1SZ = 256 * 3136;   // 802816
static constexpr int P2SZ = 512 * 784;    // 401408
static constexpr int P3SZ = 1024 * 196;   // 200704

__device__ __forceinline__ float pool9f(const float* __restrict__ p, int S, int y, int x) {
  float s = 0.f;
  for (int dy = -1; dy <= 1; ++dy) {
    int yy = y + dy; if (yy < 0 || yy >= S) continue;
    for (int dx = -1; dx <= 1; ++dx) {
      int xx = x + dx; if (xx < 0 || xx >= S) continue;
      s += p[yy * S + xx];
    }
  }
  return s * (1.f / 9.f);
}

__global__ __launch_bounds__(256) void pool_kernel(const float* __restrict__ p1, const float* __restrict__ p2,
                                                   const float* __restrict__ p3, float* __restrict__ pooled, int b) {
  int idx = blockIdx.x * 256 + threadIdx.x;          // P1SZ+P2SZ+P3SZ = 1404928 exact
  const float* src; int S, loc;
  if (idx < P1SZ)              { src = p1 + (size_t)b * P1SZ; S = 56; loc = idx; }
  else if (idx < P1SZ + P2SZ)  { src = p2 + (size_t)b * P2SZ; S = 28; loc = idx - P1SZ; }
  else                         { src = p3 + (size_t)b * P3SZ; S = 14; loc = idx - P1SZ - P2SZ; }
  int c = loc / (S * S), hw = loc % (S * S);
  pooled[idx] = pool9f(src + (size_t)c * S * S, S, hw / S, hw % S);
}

// ---------------- assemble xcb bf16 [3200][1856] pixel-major (rows>=3136 & nothing else left poison) ----------------
__global__ __launch_bounds__(256) void assemble_kernel(const float* __restrict__ pooled, uint16_t* __restrict__ xcb) {
  int idx = blockIdx.x * 256 + threadIdx.x;          // 3136*1856 exact
  int i = idx / KP1, ch = idx % KP1;
  int x = i % 56, y = i / 56;
  float v;
  if (ch < 256) {
    v = pooled[ch * 3136 + i];
  } else if (ch < 1792) {
    const float* base; int S; float scale, shift;
    if (ch < 768) { base = pooled + P1SZ + (ch - 256) * 784;          S = 28; scale = 0.5f;  shift = -0.25f;  }
    else          { base = pooled + P1SZ + P2SZ + (ch - 768) * 196;   S = 14; scale = 0.25f; shift = -0.375f; }
    float sx = x * scale + shift, sy = y * scale + shift;
    float fx0 = floorf(sx), fy0 = floorf(sy);
    float fx = sx - fx0, fy = sy - fy0;
    int x0 = (int)fx0, y0 = (int)fy0, x1 = x0 + 1, y1 = y0 + 1;
    x0 = x0 < 0 ? 0 : x0; x1 = x1 > S - 1 ? S - 1 : x1;
    y0 = y0 < 0 ? 0 : y0; y1 = y1 > S - 1 ? S - 1 : y1;
    float v00 = base[y0 * S + x0], v01 = base[y0 * S + x1];
    float v10 = base[y1 * S + x0], v11 = base[y1 * S + x1];
    v = (1.f - fy) * ((1.f - fx) * v00 + fx * v01) + fy * ((1.f - fx) * v10 + fx * v11);
  } else if (ch == 1792) v = -1.f + 2.f * x / 55.f;
  else if (ch == 1793)   v = -1.f + 2.f * y / 55.f;
  else                   v = 0.f;                    // K padding: MUST be zero
  xcb[idx] = f2bf(v);
}

// ---------------- MFMA GEMM1: phi_t[i][o] = sum_k W[o][k]*xc[i][k] + bias[o] ----------------
// A = Wh [1792][1856] (m=o), B = xcb [3200][1856] (n=i), both K-contiguous rows.
__global__ __launch_bounds__(256) void gemm1_mfma(const uint16_t* __restrict__ Wh, const float* __restrict__ bias,
                                                  const uint16_t* __restrict__ xcb, uint16_t* __restrict__ phi_t) {
  __shared__ uint16_t As[128][72];   // +8 pad: 2-way-only bank aliasing on b128 reads
  __shared__ uint16_t Bs[128][72];
  int t = threadIdx.x;
  int row0 = blockIdx.y * 128;       // o
  int col0 = blockIdx.x * 128;       // i
  int lane = t & 63, wave = t >> 6;
  int wm = wave & 1, wn = wave >> 1;
  int l15 = lane & 15, quad = lane >> 4;
  f32x4 acc[4][4] = {};
  for (int k0 = 0; k0 < KP1; k0 += 64) {
    #pragma unroll
    for (int it = 0; it < 4; ++it) {
      int idx = it * 256 + t;
      int r = idx >> 3, kc = idx & 7;
      *(uint4*)&As[r][kc * 8] = *(const uint4*)&Wh[(size_t)(row0 + r) * KP1 + k0 + kc * 8];
      *(uint4*)&Bs[r][kc * 8] = *(const uint4*)&xcb[(size_t)(col0 + r) * KP1 + k0 + kc * 8];
    }
    __syncthreads();
    #pragma unroll
    for (int kk = 0; kk < 2; ++kk) {
      int ko = kk * 32 + quad * 8;
      short8 a[4], b[4];
      #pragma unroll
      for (int i = 0; i < 4; ++i) a[i] = *(const short8*)&As[wm * 64 + i * 16 + l15][ko];
      #pragma unroll
      for (int j = 0; j < 4; ++j) b[j] = *(const short8*)&Bs[wn * 64 + j * 16 + l15][ko];
      #pragma unroll
      for (int i = 0; i < 4; ++i)
        #pragma unroll
        for (int j = 0; j < 4; ++j)
          acc[i][j] = __builtin_amdgcn_mfma_f32_16x16x32_bf16(a[i], b[j], acc[i][j], 0, 0, 0);
    }
    __syncthreads();
  }
  // D: col(lane&15)=i, row(quad*4+reg)=o. Store transposed: phi_t[i][o..o+3] as ushort4.
  #pragma unroll
  for (int i = 0; i < 4; ++i) {
    int ob = row0 + wm * 64 + i * 16 + quad * 4;
    float4 bv = *(const float4*)&bias[ob];
    float bb[4] = {bv.x, bv.y, bv.z, bv.w};
    #pragma unroll
    for (int j = 0; j < 4; ++j) {
      int ic = col0 + wn * 64 + j * 16 + l15;
      ushort4 u;
      u.x = f2bf(acc[i][j][0] + bb[0]);
      u.y = f2bf(acc[i][j][1] + bb[1]);
      u.z = f2bf(acc[i][j][2] + bb[2]);
      u.w = f2bf(acc[i][j][3] + bb[3]);
      *(ushort4*)&phi_t[(size_t)ic * ODIM + ob] = u;
    }
  }
}

// ---------------- MFMA GEMM2: key[i][j] = cent[j] - 2*sum_o phi_t[i][o]*Ct[j][o] (bf16) ----------------
__global__ __launch_bounds__(256) void gemm2_mfma(const uint16_t* __restrict__ phi_t, const uint16_t* __restrict__ Ct,
                                                  const float* __restrict__ cent, uint16_t* __restrict__ key) {
  __shared__ uint16_t As[128][72];
  __shared__ uint16_t Bs[128][72];
  int t = threadIdx.x;
  int row0 = blockIdx.y * 128;       // i (pixel)
  int col0 = blockIdx.x * 128;       // j (centroid)
  int lane = t & 63, wave = t >> 6;
  int wm = wave & 1, wn = wave >> 1;
  int l15 = lane & 15, quad = lane >> 4;
  f32x4 acc[4][4] = {};
  for (int k0 = 0; k0 < ODIM; k0 += 64) {
    #pragma unroll
    for (int it = 0; it < 4; ++it) {
      int idx = it * 256 + t;
      int r = idx >> 3, kc = idx & 7;
      *(uint4*)&As[r][kc * 8] = *(const uint4*)&phi_t[(size_t)(row0 + r) * ODIM + k0 + kc * 8];
      *(uint4*)&Bs[r][kc * 8] = *(const uint4*)&Ct[(size_t)(col0 + r) * ODIM + k0 + kc * 8];
    }
    __syncthreads();
    #pragma unroll
    for (int kk = 0; kk < 2; ++kk) {
      int ko = kk * 32 + quad * 8;
      short8 a[4], b[4];
      #pragma unroll
      for (int i = 0; i < 4; ++i) a[i] = *(const short8*)&As[wm * 64 + i * 16 + l15][ko];
      #pragma unroll
      for (int j = 0; j < 4; ++j) b[j] = *(const short8*)&Bs[wn * 64 + j * 16 + l15][ko];
      #pragma unroll
      for (int i = 0; i < 4; ++i)
        #pragma unroll
        for (int j = 0; j < 4; ++j)
          acc[i][j] = __builtin_amdgcn_mfma_f32_16x16x32_bf16(a[i], b[j], acc[i][j], 0, 0, 0);
    }
    __syncthreads();
  }
  #pragma unroll
  for (int j = 0; j < 4; ++j) {
    int jc = col0 + wn * 64 + j * 16 + l15;
    float cv = cent[jc < NCENT ? jc : 0];
    #pragma unroll
    for (int i = 0; i < 4; ++i) {
      int ib = row0 + wm * 64 + i * 16 + quad * 4;
      #pragma unroll
      for (int r = 0; r < 4; ++r)
        key[(size_t)(ib + r) * NP + jc] = f2bf(cv - 2.f * acc[i][j][r]);
    }
  }
}

// ---------------- top-3 + softmin score, one wave per row ----------------
__device__ __forceinline__ void ins3(float v, float& a, float& b, float& c) {
  if (v < c) {
    if (v < b) { c = b; if (v < a) { b = a; a = v; } else { b = v; } }
    else { c = v; }
  }
}

__global__ __launch_bounds__(256) void topk_kernel(const uint16_t* __restrict__ key, const float* __restrict__ feat,
                                                   float* __restrict__ out, int b) {
  int t = threadIdx.x, lane = t & 63, wave = t >> 6;
  int row = blockIdx.x * 4 + wave;                   // 784*4 = 3136
  const uint32_t* p = (const uint32_t*)(key + (size_t)row * NP);
  float t0 = 3.4e38f, t1 = 3.4e38f, t2 = 3.4e38f;
  for (int it = 0; it < 25; ++it) {                  // 1568 pairs, last iter partial
    int q = it * 64 + lane;
    if (q < 1568) {
      uint32_t u = p[q];
      ins3(bf2f((uint16_t)(u & 0xFFFF)), t0, t1, t2);
      ins3(bf2f((uint16_t)(u >> 16)), t0, t1, t2);
    }
  }
  #pragma unroll
  for (int m = 1; m < 64; m <<= 1) {
    float u0 = __shfl_xor(t0, m, 64);
    float u1 = __shfl_xor(t1, m, 64);
    float u2 = __shfl_xor(t2, m, 64);
    ins3(u0, t0, t1, t2); ins3(u1, t0, t1, t2); ins3(u2, t0, t1, t2);
  }
  if (lane == 0) {
    float ft = feat[row];
    float v0 = sqrtf(fmaxf(ft + t0, 0.f));
    float v1 = sqrtf(fmaxf(ft + t1, 0.f));
    float v2 = sqrtf(fmaxf(ft + t2, 0.f));
    float w0 = 1.f / (1.f + expf(v0 - v1) + expf(v0 - v2));
    out[b * HWo + row] = v0 * w0;
  }
}

// ---------------- launch ----------------
extern "C" void kernel_launch(void* const* d_in, const int* in_sizes, int n_in,
                              void* d_out, int out_size, void* d_ws, size_t ws_size,
                              hipStream_t stream) {
  const float* p1   = (const float*)d_in[0];
  const float* p2   = (const float*)d_in[1];
  const float* p3   = (const float*)d_in[2];
  const float* Wm   = (const float*)d_in[3];
  const float* bias = (const float*)d_in[4];
  const float* Cm   = (const float*)d_in[5];
  float* out = (float*)d_out;

  // workspace (~67.6 MB), all 256B-aligned
  char* ws = (char*)d_ws;
  size_t off = 0;
  uint16_t* Wh     = (uint16_t*)(ws + off); off += (size_t)ODIM * KP1 * 2;        // 6,651,904
  uint16_t* Ct     = (uint16_t*)(ws + off); off += (size_t)NP * ODIM * 2;         // 11,468,800
  float*    cent   = (float*)(ws + off);    off += 12800;
  float*    feat   = (float*)(ws + off);    off += 12800;
  float*    pooled = (float*)(ws + off);    off += (size_t)(P1SZ + P2SZ + P3SZ) * 4; // 5,619,712
  uint16_t* xcb    = (uint16_t*)(ws + off); off += (size_t)NP * KP1 * 2;          // 11,878,400
  uint16_t* phi_t  = (uint16_t*)(ws + off); off += (size_t)NP * ODIM * 2;         // 11,468,800
  uint16_t* key    = (uint16_t*)(ws + off); off += (size_t)NP * NP * 2;           // 20,480,000

  convW_kernel<<<(ODIM * KP1) / 256, 256, 0, stream>>>(Wm, Wh);
  convC_kernel<<<(NCENT * ODIM) / 256, 256, 0, stream>>>(Cm, Ct);
  rownorm_kernel<<<784, 256, 0, stream>>>(Ct, cent);

  for (int b = 0; b < NB; ++b) {
    pool_kernel<<<(P1SZ + P2SZ + P3SZ) / 256, 256, 0, stream>>>(p1, p2, p3, pooled, b);
    assemble_kernel<<<(HWo * KP1) / 256, 256, 0, stream>>>(pooled, xcb);
    gemm1_mfma<<<dim3(NP / 128, ODIM / 128), 256, 0, stream>>>(Wh, bias, xcb, phi_t);
    rownorm_kernel<<<784, 256, 0, stream>>>(phi_t, feat);
    gemm2_mfma<<<dim3(NP / 128, NP / 128), 256, 0, stream>>>(phi_t, Ct, cent, key);
    topk_kernel<<<784, 256, 0, stream>>>(key, feat, out, b);
  }
}